// Round 1
// baseline (66.639 us; speedup 1.0000x reference)
//
#include <hip/hip_runtime.h>

#define N_WORD 32000
#define DIM    300
#define BQ     32
#define WW     8
#define NNEG   2392
#define NTOT   (BQ*WW*NNEG)   // 612352
#define NBLK3  1024

// Kernel 1: tgt[b] = bag(char_emb, chars[b]) + bag(compo_emb, compos[b]),
// stored transposed tgtT[d*32 + b] for contiguous per-d access in s_kernel.
__global__ __launch_bounds__(320) void tgt_kernel(
    const float* __restrict__ char_emb, const float* __restrict__ compo_emb,
    const int* __restrict__ chars, const int* __restrict__ compos,
    float* __restrict__ tgtT) {
  int b = blockIdx.x;
  int d = threadIdx.x;
  if (d >= DIM) return;
  float a = 0.f;
  #pragma unroll
  for (int j = 0; j < 4; ++j) {
    int c = chars[b*4 + j];
    if (c != 1) a += char_emb[(size_t)c*DIM + d];
  }
  #pragma unroll
  for (int j = 0; j < 8; ++j) {
    int c = compos[b*8 + j];
    if (c != 1) a += compo_emb[(size_t)c*DIM + d];
  }
  tgtT[d*BQ + b] = a;
}

// Kernel 2: S[b][v] = tgt[b] . word_emb[v].  One thread per v, 32 accumulators.
// tgtT staged in LDS (38.4 KB), read with wave-uniform addresses (broadcast,
// conflict-free). word_emb rows read as float4 (rows are 1200 B, 16B-aligned).
__global__ __launch_bounds__(64) void s_kernel(
    const float4* __restrict__ w4, const float4* __restrict__ tgtT4,
    float* __restrict__ S) {
  __shared__ float4 t4[DIM*BQ/4];  // 2400 float4 = 38400 B
  for (int i = threadIdx.x; i < DIM*BQ/4; i += 64) t4[i] = tgtT4[i];
  __syncthreads();
  int v = blockIdx.x*64 + threadIdx.x;   // grid covers exactly 32000
  float acc[BQ];
  #pragma unroll
  for (int b = 0; b < BQ; ++b) acc[b] = 0.f;
  const float4* row = w4 + (size_t)v*(DIM/4);
  for (int j = 0; j < DIM/4; ++j) {
    float4 wv = row[j];
    float wd[4] = {wv.x, wv.y, wv.z, wv.w};
    #pragma unroll
    for (int dd = 0; dd < 4; ++dd) {
      const float4* tb = &t4[(j*4 + dd)*(BQ/4)];
      #pragma unroll
      for (int b8 = 0; b8 < BQ/4; ++b8) {
        float4 tv = tb[b8];
        acc[b8*4+0] = fmaf(wd[dd], tv.x, acc[b8*4+0]);
        acc[b8*4+1] = fmaf(wd[dd], tv.y, acc[b8*4+1]);
        acc[b8*4+2] = fmaf(wd[dd], tv.z, acc[b8*4+2]);
        acc[b8*4+3] = fmaf(wd[dd], tv.w, acc[b8*4+3]);
      }
    }
  }
  #pragma unroll
  for (int b = 0; b < BQ; ++b) S[(size_t)b*N_WORD + v] = acc[b];
}

// Kernel 3: sum log(sigmoid(-S[b, noise])) + eps term, plus the 256 positive
// terms (masked ctx => s=0 => log 0.5). Deterministic per-block partials.
__global__ __launch_bounds__(256) void loss_kernel(
    const float* __restrict__ S, const int* __restrict__ noise,
    const int* __restrict__ ctx, float* __restrict__ partials) {
  float a = 0.f;
  for (int i = blockIdx.x*256 + threadIdx.x; i < NTOT; i += 256*NBLK3) {
    int b = i / (WW*NNEG);            // constant divisor -> magic mul
    int idx = noise[i];
    float s = S[(size_t)b*N_WORD + idx];
    a += __logf(1.f/(1.f + __expf(s)) + 1e-32f);
  }
  if (blockIdx.x == 0) {
    int i = threadIdx.x;              // i = b*8 + w, covers all 256 (b,w)
    int c = ctx[i];
    float s = (c == 1) ? 0.f : S[(size_t)(i >> 3)*N_WORD + c];
    a += logf(1.f/(1.f + expf(-s)));
  }
  #pragma unroll
  for (int off = 32; off > 0; off >>= 1) a += __shfl_down(a, off);
  __shared__ float wsum[4];
  int lane = threadIdx.x & 63, wid = threadIdx.x >> 6;
  if (lane == 0) wsum[wid] = a;
  __syncthreads();
  if (threadIdx.x == 0)
    partials[blockIdx.x] = wsum[0] + wsum[1] + wsum[2] + wsum[3];
}

// Kernel 4: deterministic final reduction in double; out = -total / B.
__global__ __launch_bounds__(256) void final_kernel(
    const float* __restrict__ partials, float* __restrict__ out) {
  double a = 0.0;
  for (int i = threadIdx.x; i < NBLK3; i += 256) a += (double)partials[i];
  #pragma unroll
  for (int off = 32; off > 0; off >>= 1) a += __shfl_down(a, off);
  __shared__ double w2[4];
  int lane = threadIdx.x & 63, wid = threadIdx.x >> 6;
  if (lane == 0) w2[wid] = a;
  __syncthreads();
  if (threadIdx.x == 0)
    out[0] = (float)(-(w2[0] + w2[1] + w2[2] + w2[3]) / (double)BQ);
}

extern "C" void kernel_launch(void* const* d_in, const int* in_sizes, int n_in,
                              void* d_out, int out_size, void* d_ws, size_t ws_size,
                              hipStream_t stream) {
  const float* word_emb  = (const float*)d_in[0];   // [32000,300]
  const float* char_emb  = (const float*)d_in[1];   // [8000,300]
  const float* compo_emb = (const float*)d_in[2];   // [1000,300]
  const int*   chars     = (const int*)d_in[3];     // [32,4]
  const int*   compos    = (const int*)d_in[4];     // [32,8]
  const int*   ctx       = (const int*)d_in[5];     // [32,8]
  const int*   noise     = (const int*)d_in[6];     // [32,8,2392]
  float* out = (float*)d_out;

  float* ws       = (float*)d_ws;
  float* tgtT     = ws;                              // 9600 floats
  float* S        = ws + DIM*BQ;                     // 1,024,000 floats
  float* partials = S + (size_t)BQ*N_WORD;           // NBLK3 floats

  tgt_kernel<<<BQ, 320, 0, stream>>>(char_emb, compo_emb, chars, compos, tgtT);
  s_kernel<<<N_WORD/64, 64, 0, stream>>>((const float4*)word_emb,
                                         (const float4*)tgtT, S);
  loss_kernel<<<NBLK3, 256, 0, stream>>>(S, noise, ctx, partials);
  final_kernel<<<1, 256, 0, stream>>>(partials, out);
}

// Round 2
// 59.927 us; speedup vs baseline: 1.1120x; 1.1120x over previous
//
#include <hip/hip_runtime.h>

#define N_WORD 32000
#define DIM    300
#define NJ_TOT 75            // DIM/4 float4 per embedding row
#define BQ     32
#define WW     8
#define NNEG   2392
#define NTOT   (BQ*WW*NNEG)  // 612352
#define NBLK3  1024

// Kernel 1: tgt[b] = bag(char_emb, chars[b]) + bag(compo_emb, compos[b]),
// stored transposed tgtT[d*32 + b].
__global__ __launch_bounds__(320) void tgt_kernel(
    const float* __restrict__ char_emb, const float* __restrict__ compo_emb,
    const int* __restrict__ chars, const int* __restrict__ compos,
    float* __restrict__ tgtT) {
  int b = blockIdx.x;
  int d = threadIdx.x;
  if (d >= DIM) return;
  float a = 0.f;
  #pragma unroll
  for (int j = 0; j < 4; ++j) {
    int c = chars[b*4 + j];
    if (c != 1) a += char_emb[(size_t)c*DIM + d];
  }
  #pragma unroll
  for (int j = 0; j < 8; ++j) {
    int c = compos[b*8 + j];
    if (c != 1) a += compo_emb[(size_t)c*DIM + d];
  }
  tgtT[d*BQ + b] = a;
}

// Kernel 2: partial scores Sp[c][b][v] = sum over dim-chunk c of tgt[b][d]*W[v][d].
// blockIdx.x: v-block of 256 (128 threads x 2 v each); blockIdx.y: k-chunk.
// Each thread owns 2 word rows (v, v+64): every tgt float4 read from LDS feeds
// 8 FMAs (4 dims x 2 v), and two independent global streams give MLP.
__global__ __launch_bounds__(128, 2) void s_kernel(
    const float4* __restrict__ w4, const float4* __restrict__ tgtT4,
    float* __restrict__ Sp, int ks) {
  int c  = blockIdx.y;
  int base = NJ_TOT / ks, rem = NJ_TOT % ks;
  int j0 = c*base + (c < rem ? c : rem);
  int nj = base + (c < rem ? 1 : 0);

  extern __shared__ float4 tl4[];          // [nj*4 dims][8] float4 of tgtT
  int nf = nj*32;                           // float4 count
  for (int i = threadIdx.x; i < nf; i += 128) tl4[i] = tgtT4[j0*32 + i];
  __syncthreads();

  int wave = threadIdx.x >> 6, lane = threadIdx.x & 63;
  int vbase = blockIdx.x*256 + wave*128;
  int v0 = vbase + lane, v1 = v0 + 64;

  float a0[BQ], a1[BQ];
  #pragma unroll
  for (int b = 0; b < BQ; ++b) { a0[b] = 0.f; a1[b] = 0.f; }

  const float4* r0 = w4 + (size_t)v0*NJ_TOT + j0;
  const float4* r1 = w4 + (size_t)v1*NJ_TOT + j0;
  float4 x0 = r0[0], x1 = r1[0];
  for (int j = 0; j < nj; ++j) {
    float4 n0, n1;
    if (j + 1 < nj) { n0 = r0[j+1]; n1 = r1[j+1]; }   // 1-deep prefetch
    float xd0[4] = {x0.x, x0.y, x0.z, x0.w};
    float xd1[4] = {x1.x, x1.y, x1.z, x1.w};
    #pragma unroll
    for (int dd = 0; dd < 4; ++dd) {
      const float4* tb = &tl4[(j*4 + dd)*8];
      #pragma unroll
      for (int b8 = 0; b8 < 8; ++b8) {
        float4 tv = tb[b8];   // wave-uniform broadcast read, reused for v0 & v1
        a0[b8*4+0] = fmaf(xd0[dd], tv.x, a0[b8*4+0]);
        a0[b8*4+1] = fmaf(xd0[dd], tv.y, a0[b8*4+1]);
        a0[b8*4+2] = fmaf(xd0[dd], tv.z, a0[b8*4+2]);
        a0[b8*4+3] = fmaf(xd0[dd], tv.w, a0[b8*4+3]);
        a1[b8*4+0] = fmaf(xd1[dd], tv.x, a1[b8*4+0]);
        a1[b8*4+1] = fmaf(xd1[dd], tv.y, a1[b8*4+1]);
        a1[b8*4+2] = fmaf(xd1[dd], tv.z, a1[b8*4+2]);
        a1[b8*4+3] = fmaf(xd1[dd], tv.w, a1[b8*4+3]);
      }
    }
    x0 = n0; x1 = n1;
  }
  float* Sc = Sp + (size_t)c*BQ*N_WORD;
  #pragma unroll
  for (int b = 0; b < BQ; ++b) {
    Sc[(size_t)b*N_WORD + v0] = a0[b];
    Sc[(size_t)b*N_WORD + v1] = a1[b];
  }
}

// Kernel 3: fold ks partials at gather time; sum log sigmoid terms.
__global__ __launch_bounds__(256) void loss_kernel(
    const float* __restrict__ Sp, const int* __restrict__ noise,
    const int* __restrict__ ctx, float* __restrict__ partials, int ks) {
  float a = 0.f;
  for (int i = blockIdx.x*256 + threadIdx.x; i < NTOT; i += 256*NBLK3) {
    int b = i / (WW*NNEG);
    int idx = noise[i];
    size_t off = (size_t)b*N_WORD + idx;
    float s = 0.f;
    #pragma unroll 4
    for (int cc = 0; cc < ks; ++cc) s += Sp[off + (size_t)cc*BQ*N_WORD];
    a += __logf(1.f/(1.f + __expf(s)) + 1e-32f);
  }
  if (blockIdx.x == 0) {
    int i = threadIdx.x;             // i = b*8 + w covers all 256 (b,w)
    int c = ctx[i];
    float s = 0.f;
    if (c != 1) {
      size_t off = (size_t)(i >> 3)*N_WORD + c;
      #pragma unroll 4
      for (int cc = 0; cc < ks; ++cc) s += Sp[off + (size_t)cc*BQ*N_WORD];
    }
    a += logf(1.f/(1.f + expf(-s)));
  }
  #pragma unroll
  for (int off = 32; off > 0; off >>= 1) a += __shfl_down(a, off);
  __shared__ float wsum[4];
  int lane = threadIdx.x & 63, wid = threadIdx.x >> 6;
  if (lane == 0) wsum[wid] = a;
  __syncthreads();
  if (threadIdx.x == 0)
    partials[blockIdx.x] = wsum[0] + wsum[1] + wsum[2] + wsum[3];
}

// Kernel 4: deterministic final reduction in double; out = -total / B.
__global__ __launch_bounds__(256) void final_kernel(
    const float* __restrict__ partials, float* __restrict__ out) {
  double a = 0.0;
  for (int i = threadIdx.x; i < NBLK3; i += 256) a += (double)partials[i];
  #pragma unroll
  for (int off = 32; off > 0; off >>= 1) a += __shfl_down(a, off);
  __shared__ double w2[4];
  int lane = threadIdx.x & 63, wid = threadIdx.x >> 6;
  if (lane == 0) w2[wid] = a;
  __syncthreads();
  if (threadIdx.x == 0)
    out[0] = (float)(-(w2[0] + w2[1] + w2[2] + w2[3]) / (double)BQ);
}

extern "C" void kernel_launch(void* const* d_in, const int* in_sizes, int n_in,
                              void* d_out, int out_size, void* d_ws, size_t ws_size,
                              hipStream_t stream) {
  const float* word_emb  = (const float*)d_in[0];   // [32000,300]
  const float* char_emb  = (const float*)d_in[1];   // [8000,300]
  const float* compo_emb = (const float*)d_in[2];   // [1000,300]
  const int*   chars     = (const int*)d_in[3];     // [32,4]
  const int*   compos    = (const int*)d_in[4];     // [32,8]
  const int*   ctx       = (const int*)d_in[5];     // [32,8]
  const int*   noise     = (const int*)d_in[6];     // [32,8,2392]
  float* out = (float*)d_out;

  // pick largest k-split whose partial tables fit the workspace
  size_t fixed = (size_t)(DIM*BQ + NBLK3) * sizeof(float);
  int ks = 4;
  while (ks > 1 && fixed + (size_t)ks*BQ*N_WORD*sizeof(float) > ws_size) ks >>= 1;

  float* ws       = (float*)d_ws;
  float* tgtT     = ws;                               // 9600 floats
  float* Sp       = ws + DIM*BQ;                      // ks * 1,024,000 floats
  float* partials = Sp + (size_t)ks*BQ*N_WORD;        // NBLK3 floats

  int base = NJ_TOT / ks, rem = NJ_TOT % ks;
  int nj_max = base + (rem ? 1 : 0);
  size_t lds_bytes = (size_t)nj_max * 4 * BQ * sizeof(float);  // <= 38400

  tgt_kernel<<<BQ, 320, 0, stream>>>(char_emb, compo_emb, chars, compos, tgtT);
  s_kernel<<<dim3(125, ks), 128, lds_bytes, stream>>>(
      (const float4*)word_emb, (const float4*)tgtT, Sp, ks);
  loss_kernel<<<NBLK3, 256, 0, stream>>>(Sp, noise, ctx, partials, ks);
  final_kernel<<<1, 256, 0, stream>>>(partials, out);
}